// Round 1
// baseline (394.293 us; speedup 1.0000x reference)
//
#include <hip/hip_runtime.h>
#include <hip/hip_bf16.h>
#include <stdint.h>

typedef __attribute__((ext_vector_type(8))) short bf16x8;
typedef __attribute__((ext_vector_type(4))) float f32x4;

// ---------------- threefry2x32 (exact JAX) ----------------
__host__ __device__ __forceinline__ uint32_t rotl32(uint32_t x, int d){
  return (x << d) | (x >> (32 - d));
}

__host__ __device__ inline void threefry2x32(uint32_t k0, uint32_t k1,
                                             uint32_t x0, uint32_t x1,
                                             uint32_t* o0, uint32_t* o1){
  uint32_t ks2 = k0 ^ k1 ^ 0x1BD11BDAu;
  x0 += k0; x1 += k1;
  // group 1: rotations [13,15,26,6]
  x0 += x1; x1 = rotl32(x1,13); x1 ^= x0;
  x0 += x1; x1 = rotl32(x1,15); x1 ^= x0;
  x0 += x1; x1 = rotl32(x1,26); x1 ^= x0;
  x0 += x1; x1 = rotl32(x1, 6); x1 ^= x0;
  x0 += k1; x1 += ks2 + 1u;
  // group 2: [17,29,16,24]
  x0 += x1; x1 = rotl32(x1,17); x1 ^= x0;
  x0 += x1; x1 = rotl32(x1,29); x1 ^= x0;
  x0 += x1; x1 = rotl32(x1,16); x1 ^= x0;
  x0 += x1; x1 = rotl32(x1,24); x1 ^= x0;
  x0 += ks2; x1 += k0 + 2u;
  // group 3
  x0 += x1; x1 = rotl32(x1,13); x1 ^= x0;
  x0 += x1; x1 = rotl32(x1,15); x1 ^= x0;
  x0 += x1; x1 = rotl32(x1,26); x1 ^= x0;
  x0 += x1; x1 = rotl32(x1, 6); x1 ^= x0;
  x0 += k0; x1 += k1 + 3u;
  // group 4
  x0 += x1; x1 = rotl32(x1,17); x1 ^= x0;
  x0 += x1; x1 = rotl32(x1,29); x1 ^= x0;
  x0 += x1; x1 = rotl32(x1,16); x1 ^= x0;
  x0 += x1; x1 = rotl32(x1,24); x1 ^= x0;
  x0 += k1; x1 += ks2 + 4u;
  // group 5
  x0 += x1; x1 = rotl32(x1,13); x1 ^= x0;
  x0 += x1; x1 = rotl32(x1,15); x1 ^= x0;
  x0 += x1; x1 = rotl32(x1,26); x1 ^= x0;
  x0 += x1; x1 = rotl32(x1, 6); x1 ^= x0;
  x0 += ks2; x1 += k0 + 5u;
  *o0 = x0; *o1 = x1;
}

// Partitionable semantics: bits(j) = o0 ^ o1 of threefry(key, (0, j)).
// uniform = ((bits>>9)|0x3f800000)-1 ; keep iff uniform < 0.5 iff MSB(bits)==0.
// Returns the dropout scale (2.0 if kept, 0.0 if dropped).
__device__ __forceinline__ float tf_scale(uint32_t k0, uint32_t k1, uint32_t j){
  uint32_t o0, o1;
  threefry2x32(k0, k1, 0u, j, &o0, &o1);
  return ((o0 ^ o1) >> 31) ? 0.0f : 2.0f;
}

// ---------------- bf16 helpers (raw ushort) ----------------
__device__ __forceinline__ ushort f2bf(float f){
  uint32_t u = __float_as_uint(f);
  u += 0x7FFFu + ((u >> 16) & 1u);   // round-nearest-even
  return (ushort)(u >> 16);
}
__device__ __forceinline__ float bf2f(ushort b){
  return __uint_as_float(((uint32_t)b) << 16);
}

// ---------------- K0: row_ptr via binary search + zero probs acc ----------------
__global__ void k_init(const int* __restrict__ rowv, int* __restrict__ rp,
                       float* __restrict__ pacc, int N, int E){
  int i = blockIdx.x * 256 + threadIdx.x;
  if (i == 0) pacc[0] = 0.0f;
  if (i <= N){
    int lo = 0, hi = E;
    while (lo < hi){
      int mid = (lo + hi) >> 1;
      if (rowv[mid] < i) lo = mid + 1; else hi = mid;
    }
    rp[i] = lo;
  }
}

// ---------------- K1: support1 = dropout(x) @ W1 (bf16 MFMA) ----------------
// block = 256 threads = 4 waves, 64 rows per block, K split in 2 halves of 256.
__global__ __launch_bounds__(256) void k_gemm1(
    const float* __restrict__ x, const float* __restrict__ W1,
    ushort* __restrict__ s1, uint32_t dk0, uint32_t dk1, int N){
  __shared__ __align__(16) ushort aT[32 * 64 * 8];  // [kc 0..31][row 0..63][8 bf16] = 32KB
  __shared__ __align__(16) ushort bW[64 * 16 * 8];  // [kcg 0..63][col 0..15][8 bf16] = 16KB
  int t = threadIdx.x;
  int r0 = blockIdx.x * 64;

  // stage W1 -> bf16 LDS, layout [f>>3][col][f&7]
  for (int u = 0; u < 32; ++u){
    int idx = u * 256 + t;            // = f*16 + c
    int f = idx >> 4, c = idx & 15;
    bW[((f >> 3) * 16 + c) * 8 + (f & 7)] = f2bf(W1[idx]);
  }

  int l  = t & 63, w = t >> 6;
  int rA = l & 15, kg = l >> 4;
  f32x4 acc = {0.f, 0.f, 0.f, 0.f};

  for (int half = 0; half < 2; ++half){
    __syncthreads();   // protects aT reuse (and publishes bW on first pass)
    // stage 64 rows x 256 cols of masked x as bf16
    for (int u = 0; u < 16; ++u){
      int elem = (u * 256 + t) * 4;    // within 64x256 tile
      int rowi = elem >> 8;            // 0..63
      int fl   = elem & 255;           // multiple of 4
      int n = r0 + rowi;
      int f = half * 256 + fl;
      ushort v0, v1, v2, v3;
      if (n < N){
        const float4 xv = *reinterpret_cast<const float4*>(x + (size_t)n * 512 + f);
        uint32_t jb = (uint32_t)n * 512u + (uint32_t)f;
        v0 = f2bf(xv.x * tf_scale(dk0, dk1, jb + 0u));
        v1 = f2bf(xv.y * tf_scale(dk0, dk1, jb + 1u));
        v2 = f2bf(xv.z * tf_scale(dk0, dk1, jb + 2u));
        v3 = f2bf(xv.w * tf_scale(dk0, dk1, jb + 3u));
      } else { v0 = v1 = v2 = v3 = 0; }
      ushort4 pv; pv.x = v0; pv.y = v1; pv.z = v2; pv.w = v3;
      *reinterpret_cast<ushort4*>(&aT[((fl >> 3) * 64 + rowi) * 8 + (fl & 7)]) = pv;
    }
    __syncthreads();
    // 8 MFMA chunks of K=32 per half
    for (int kc0 = 0; kc0 < 8; ++kc0){
      int kcl = kc0 * 4 + kg;          // 8-wide k-chunk within half
      bf16x8 a = *reinterpret_cast<const bf16x8*>(&aT[(kcl * 64 + (w * 16 + rA)) * 8]);
      int kcg = half * 32 + kcl;
      bf16x8 b = *reinterpret_cast<const bf16x8*>(&bW[(kcg * 16 + rA) * 8]);
      acc = __builtin_amdgcn_mfma_f32_16x16x32_bf16(a, b, acc, 0, 0, 0);
    }
  }
  // C/D: col = lane&15, row = (lane>>4)*4 + reg
  for (int i2 = 0; i2 < 4; ++i2){
    int n = r0 + w * 16 + kg * 4 + i2;
    if (n < N) s1[(size_t)n * 16 + rA] = f2bf(acc[i2]);
  }
}

// ---------------- K2: h = spmm(support1); fused GMM-probs, relu, dropout2, @W2 ----------------
__global__ __launch_bounds__(256) void k_spmm1(
    const float* __restrict__ adj, const int* __restrict__ colv,
    const int* __restrict__ rp, const ushort* __restrict__ s1,
    const float* __restrict__ PI, const float* __restrict__ MUs,
    const float* __restrict__ PREs, const float* __restrict__ W2,
    float* __restrict__ s2, float* __restrict__ pacc,
    uint32_t dk0, uint32_t dk1, int N){
  __shared__ float mu[256], pre[256], w2[256], ck[16];
  __shared__ float bsum;
  int t = threadIdx.x;
  mu[t]  = MUs[t];
  pre[t] = PREs[t];
  w2[t]  = W2[t];
  if (t == 0) bsum = 0.f;
  __syncthreads();
  if (t < 16){
    float s = logf(PI[t]);
    #pragma unroll
    for (int j = 0; j < 16; ++j) s += 0.5f * logf(pre[t * 16 + j]);
    ck[t] = s - 8.0f * logf(6.28318530717958647692f);  // - HALF_D_LOG_2PI * log(2*pi)
  }
  __syncthreads();

  int i = blockIdx.x * 16 + (t >> 4);
  int d = t & 15;
  int base = t & 48;   // 16-lane group base within wave
  float h = 0.f;
  if (i < N){
    int e0 = rp[i], e1 = rp[i + 1];
    for (int e = e0; e < e1; ++e)
      h += adj[e] * bf2f(s1[(size_t)colv[e] * 16 + d]);
  }
  // GMM log-likelihood: lane's component k = d
  float lc = ck[d];
  #pragma unroll
  for (int j = 0; j < 16; ++j){
    float hj = __shfl(h, base + j, 64);
    float df = hj - mu[d * 16 + j];
    lc -= 0.5f * df * df * pre[d * 16 + j];
  }
  float m = lc;
  #pragma unroll
  for (int s = 1; s < 16; s <<= 1) m = fmaxf(m, __shfl_xor(m, s, 64));
  if (d == 0 && i < N) atomicAdd(&bsum, m);
  // relu -> dropout (key dk2) -> @W2
  float v = fmaxf(h, 0.f);
  float xd2 = (i < N) ? tf_scale(dk0, dk1, (uint32_t)i * 16u + (uint32_t)d) * v : 0.f;
  float s2v = 0.f;
  #pragma unroll
  for (int j = 0; j < 16; ++j){
    float xj = __shfl(xd2, base + j, 64);
    s2v += xj * w2[j * 16 + d];
  }
  if (i < N) s2[(size_t)i * 16 + d] = s2v;
  __syncthreads();
  if (t == 0) atomicAdd(pacc, bsum);
}

// ---------------- K3: h2 = spmm(support2); log_softmax ----------------
__global__ __launch_bounds__(256) void k_spmm2(
    const float* __restrict__ adj, const int* __restrict__ colv,
    const int* __restrict__ rp, const float* __restrict__ s2,
    float* __restrict__ out, int N){
  int t = threadIdx.x;
  int i = blockIdx.x * 16 + (t >> 4);
  int d = t & 15;
  float h = 0.f;
  if (i < N){
    int e0 = rp[i], e1 = rp[i + 1];
    for (int e = e0; e < e1; ++e)
      h += adj[e] * s2[(size_t)colv[e] * 16 + d];
  }
  float m = h;
  #pragma unroll
  for (int s = 1; s < 16; s <<= 1) m = fmaxf(m, __shfl_xor(m, s, 64));
  float ex = expf(h - m);
  float ssum = ex;
  #pragma unroll
  for (int s = 1; s < 16; s <<= 1) ssum += __shfl_xor(ssum, s, 64);
  if (i < N) out[(size_t)i * 16 + d] = (h - m) - logf(ssum);
}

// ---------------- K4: finalize probs ----------------
__global__ void k_fin(const float* __restrict__ pacc, float* __restrict__ out, int N){
  if (threadIdx.x == 0 && blockIdx.x == 0)
    out[(size_t)N * 16] = -pacc[0] / (float)N;
}

extern "C" void kernel_launch(void* const* d_in, const int* in_sizes, int n_in,
                              void* d_out, int out_size, void* d_ws, size_t ws_size,
                              hipStream_t stream){
  const float* x    = (const float*)d_in[0];
  const float* W1   = (const float*)d_in[1];
  const float* W2   = (const float*)d_in[2];
  const float* adj  = (const float*)d_in[3];
  const float* PI   = (const float*)d_in[4];
  const float* MUs  = (const float*)d_in[5];
  const float* PREs = (const float*)d_in[6];
  const int*   rowv = (const int*)d_in[7];
  const int*   colv = (const int*)d_in[8];
  const int N = in_sizes[0] / 512;   // 100000
  const int E = in_sizes[3];         // 3200000
  float* out = (float*)d_out;

  // workspace layout
  char* ws = (char*)d_ws;
  float* pacc = (float*)ws;                                   // 1 float
  int*   rp   = (int*)(ws + 256);                             // N+1 ints
  size_t rpBytes = (((size_t)(N + 1) * 4) + 255) & ~(size_t)255;
  ushort* s1 = (ushort*)(ws + 256 + rpBytes);                 // N*16 bf16
  float*  s2 = (float*)(ws + 256 + rpBytes + (((size_t)N * 16 * 2 + 255) & ~(size_t)255));

  // derive dk1/dk2 on host: fold-like split of key(42) = (0, 42)
  uint32_t d10, d11, d20, d21;
  threefry2x32(0u, 42u, 0u, 0u, &d10, &d11);  // dk1
  threefry2x32(0u, 42u, 0u, 1u, &d20, &d21);  // dk2

  int nb0 = (N + 1 + 255) / 256;
  k_init<<<nb0, 256, 0, stream>>>(rowv, rp, pacc, N, E);
  int nb1 = (N + 63) / 64;
  k_gemm1<<<nb1, 256, 0, stream>>>(x, W1, s1, d10, d11, N);
  int nb2 = (N + 15) / 16;
  k_spmm1<<<nb2, 256, 0, stream>>>(adj, colv, rp, s1, PI, MUs, PREs, W2,
                                   s2, pacc, d20, d21, N);
  k_spmm2<<<nb2, 256, 0, stream>>>(adj, colv, rp, s2, out, N);
  k_fin<<<1, 64, 0, stream>>>(pacc, out, N);
}

// Round 2
// 378.094 us; speedup vs baseline: 1.0428x; 1.0428x over previous
//
#include <hip/hip_runtime.h>
#include <hip/hip_bf16.h>
#include <stdint.h>

typedef __attribute__((ext_vector_type(8))) short bf16x8;
typedef __attribute__((ext_vector_type(4))) float f32x4;

// ---------------- threefry2x32 (exact JAX) ----------------
__host__ __device__ __forceinline__ uint32_t rotl32(uint32_t x, int d){
  return (x << d) | (x >> (32 - d));
}

__host__ __device__ inline void threefry2x32(uint32_t k0, uint32_t k1,
                                             uint32_t x0, uint32_t x1,
                                             uint32_t* o0, uint32_t* o1){
  uint32_t ks2 = k0 ^ k1 ^ 0x1BD11BDAu;
  x0 += k0; x1 += k1;
  x0 += x1; x1 = rotl32(x1,13); x1 ^= x0;
  x0 += x1; x1 = rotl32(x1,15); x1 ^= x0;
  x0 += x1; x1 = rotl32(x1,26); x1 ^= x0;
  x0 += x1; x1 = rotl32(x1, 6); x1 ^= x0;
  x0 += k1; x1 += ks2 + 1u;
  x0 += x1; x1 = rotl32(x1,17); x1 ^= x0;
  x0 += x1; x1 = rotl32(x1,29); x1 ^= x0;
  x0 += x1; x1 = rotl32(x1,16); x1 ^= x0;
  x0 += x1; x1 = rotl32(x1,24); x1 ^= x0;
  x0 += ks2; x1 += k0 + 2u;
  x0 += x1; x1 = rotl32(x1,13); x1 ^= x0;
  x0 += x1; x1 = rotl32(x1,15); x1 ^= x0;
  x0 += x1; x1 = rotl32(x1,26); x1 ^= x0;
  x0 += x1; x1 = rotl32(x1, 6); x1 ^= x0;
  x0 += k0; x1 += k1 + 3u;
  x0 += x1; x1 = rotl32(x1,17); x1 ^= x0;
  x0 += x1; x1 = rotl32(x1,29); x1 ^= x0;
  x0 += x1; x1 = rotl32(x1,16); x1 ^= x0;
  x0 += x1; x1 = rotl32(x1,24); x1 ^= x0;
  x0 += k1; x1 += ks2 + 4u;
  x0 += x1; x1 = rotl32(x1,13); x1 ^= x0;
  x0 += x1; x1 = rotl32(x1,15); x1 ^= x0;
  x0 += x1; x1 = rotl32(x1,26); x1 ^= x0;
  x0 += x1; x1 = rotl32(x1, 6); x1 ^= x0;
  x0 += ks2; x1 += k0 + 5u;
  *o0 = x0; *o1 = x1;
}

// Partitionable semantics: bits(j) = o0^o1 of threefry(key,(0,j)); drop iff MSB set.
__device__ __forceinline__ uint32_t tf_dropbit(uint32_t k0, uint32_t k1, uint32_t j){
  uint32_t o0, o1;
  threefry2x32(k0, k1, 0u, j, &o0, &o1);
  return (o0 ^ o1) >> 31;   // 1 = drop
}

// ---------------- bf16 helpers (raw ushort) ----------------
__device__ __forceinline__ ushort f2bf(float f){
  uint32_t u = __float_as_uint(f);
  u += 0x7FFFu + ((u >> 16) & 1u);   // round-nearest-even
  return (ushort)(u >> 16);
}
__device__ __forceinline__ float bf2f(ushort b){
  return __uint_as_float(((uint32_t)b) << 16);
}

// ---------------- K0: row_ptr via binary search + zero probs acc ----------------
__global__ void k_init(const int* __restrict__ rowv, int* __restrict__ rp,
                       float* __restrict__ pacc, int N, int E){
  int i = blockIdx.x * 256 + threadIdx.x;
  if (i == 0) pacc[0] = 0.0f;
  if (i <= N){
    int lo = 0, hi = E;
    while (lo < hi){
      int mid = (lo + hi) >> 1;
      if (rowv[mid] < i) lo = mid + 1; else hi = mid;
    }
    rp[i] = lo;
  }
}

// ---------------- K1: support1 = dropout(x) @ W1 (bf16 MFMA, no A-staging) ----
// 1 wave = 1 tile of 16 rows. A-fragment loaded straight from global (the k-map
// (lane>>4)*8+e is used identically for A and B, so HW k-permutation cancels).
// Dropout scale 2.0 folded into the W1 staging; dropped elements are exact 0.
__global__ __launch_bounds__(256) void k_gemm1(
    const float* __restrict__ x, const float* __restrict__ W1,
    ushort* __restrict__ s1, uint32_t dk0, uint32_t dk1, int ntiles){
  __shared__ __align__(16) ushort bW[64 * 16 * 8];  // 16KB: [k>>3][col][k&7] of 2*W1 (bf16)
  int t = threadIdx.x;
  for (int u = 0; u < 32; ++u){
    int idx = u * 256 + t;            // = k*16 + c
    int k = idx >> 4, c = idx & 15;
    bW[((k >> 3) * 16 + c) * 8 + (k & 7)] = f2bf(2.0f * W1[idx]);
  }
  __syncthreads();

  int l = t & 63, w = t >> 6;
  int rA = l & 15, kg = l >> 4;
  int tile = blockIdx.x * 4 + w;
  if (tile >= ntiles) return;
  int r0 = tile * 16;

  const float* xp = x + (size_t)(r0 + rA) * 512 + kg * 8;
  uint32_t jb = (uint32_t)(r0 + rA) * 512u + (uint32_t)(kg * 8);
  f32x4 acc = {0.f, 0.f, 0.f, 0.f};

  float4 xa = *reinterpret_cast<const float4*>(xp);
  float4 xb = *reinterpret_cast<const float4*>(xp + 4);

  auto body = [&](int ks, float4 va, float4 vb){
    uint32_t j0 = jb + (uint32_t)(ks * 32);
    uint32_t drop[8];
    #pragma unroll
    for (int e = 0; e < 8; ++e) drop[e] = tf_dropbit(dk0, dk1, j0 + (uint32_t)e);
    float v[8] = {va.x, va.y, va.z, va.w, vb.x, vb.y, vb.z, vb.w};
    bf16x8 a;
    #pragma unroll
    for (int e = 0; e < 8; ++e) a[e] = drop[e] ? (short)0 : (short)f2bf(v[e]);
    bf16x8 b = *reinterpret_cast<const bf16x8*>(&bW[((ks * 4 + kg) * 16 + rA) * 8]);
    acc = __builtin_amdgcn_mfma_f32_16x16x32_bf16(a, b, acc, 0, 0, 0);
  };

  for (int ks = 0; ks < 15; ++ks){
    float4 na = *reinterpret_cast<const float4*>(xp + (ks + 1) * 32);
    float4 nb = *reinterpret_cast<const float4*>(xp + (ks + 1) * 32 + 4);
    body(ks, xa, xb);
    xa = na; xb = nb;
  }
  body(15, xa, xb);

  // C/D: col = lane&15, row = (lane>>4)*4 + reg
  #pragma unroll
  for (int i2 = 0; i2 < 4; ++i2)
    s1[(size_t)(r0 + kg * 4 + i2) * 16 + rA] = f2bf(acc[i2]);
}

// ---------------- K2: h = spmm(support1); fused GMM-probs, relu, dropout2, @W2 ----------------
__global__ __launch_bounds__(256) void k_spmm1(
    const float* __restrict__ adj, const int* __restrict__ colv,
    const int* __restrict__ rp, const ushort* __restrict__ s1,
    const float* __restrict__ PI, const float* __restrict__ MUs,
    const float* __restrict__ PREs, const float* __restrict__ W2,
    float* __restrict__ s2, float* __restrict__ pacc,
    uint32_t dk0, uint32_t dk1, int N){
  __shared__ float mu[256], pre[256], w2[256], ck[16];
  __shared__ float bsum;
  int t = threadIdx.x;
  mu[t]  = MUs[t];
  pre[t] = PREs[t];
  w2[t]  = W2[t];
  if (t == 0) bsum = 0.f;
  __syncthreads();
  if (t < 16){
    float s = logf(PI[t]);
    #pragma unroll
    for (int j = 0; j < 16; ++j) s += 0.5f * logf(pre[t * 16 + j]);
    ck[t] = s - 8.0f * logf(6.28318530717958647692f);
  }
  __syncthreads();

  int i = blockIdx.x * 16 + (t >> 4);
  int d = t & 15;
  int base = t & 48;
  float h = 0.f;
  if (i < N){
    int e0 = rp[i], e1 = rp[i + 1];
    for (int e = e0; e < e1; ++e)
      h += adj[e] * bf2f(s1[(size_t)colv[e] * 16 + d]);
  }
  // GMM log-likelihood: lane's component k = d
  float lc = ck[d];
  #pragma unroll
  for (int j = 0; j < 16; ++j){
    float hj = __shfl(h, base + j, 64);
    float df = hj - mu[d * 16 + j];
    lc -= 0.5f * df * df * pre[d * 16 + j];
  }
  float m = lc;
  #pragma unroll
  for (int s = 1; s < 16; s <<= 1) m = fmaxf(m, __shfl_xor(m, s, 64));
  if (d == 0 && i < N) atomicAdd(&bsum, m);
  // relu -> dropout (key dk2) -> @W2
  float v = fmaxf(h, 0.f);
  float xd2 = (i < N && !tf_dropbit(dk0, dk1, (uint32_t)i * 16u + (uint32_t)d))
              ? 2.0f * v : 0.f;
  float s2v = 0.f;
  #pragma unroll
  for (int j = 0; j < 16; ++j){
    float xj = __shfl(xd2, base + j, 64);
    s2v += xj * w2[j * 16 + d];
  }
  if (i < N) s2[(size_t)i * 16 + d] = s2v;
  __syncthreads();
  if (t == 0) atomicAdd(pacc, bsum);
}

// ---------------- K3: h2 = spmm(support2); log_softmax ----------------
__global__ __launch_bounds__(256) void k_spmm2(
    const float* __restrict__ adj, const int* __restrict__ colv,
    const int* __restrict__ rp, const float* __restrict__ s2,
    float* __restrict__ out, int N){
  int t = threadIdx.x;
  int i = blockIdx.x * 16 + (t >> 4);
  int d = t & 15;
  float h = 0.f;
  if (i < N){
    int e0 = rp[i], e1 = rp[i + 1];
    for (int e = e0; e < e1; ++e)
      h += adj[e] * s2[(size_t)colv[e] * 16 + d];
  }
  float m = h;
  #pragma unroll
  for (int s = 1; s < 16; s <<= 1) m = fmaxf(m, __shfl_xor(m, s, 64));
  float ex = expf(h - m);
  float ssum = ex;
  #pragma unroll
  for (int s = 1; s < 16; s <<= 1) ssum += __shfl_xor(ssum, s, 64);
  if (i < N) out[(size_t)i * 16 + d] = (h - m) - logf(ssum);
}

// ---------------- K4: finalize probs ----------------
__global__ void k_fin(const float* __restrict__ pacc, float* __restrict__ out, int N){
  if (threadIdx.x == 0 && blockIdx.x == 0)
    out[(size_t)N * 16] = -pacc[0] / (float)N;
}

extern "C" void kernel_launch(void* const* d_in, const int* in_sizes, int n_in,
                              void* d_out, int out_size, void* d_ws, size_t ws_size,
                              hipStream_t stream){
  const float* x    = (const float*)d_in[0];
  const float* W1   = (const float*)d_in[1];
  const float* W2   = (const float*)d_in[2];
  const float* adj  = (const float*)d_in[3];
  const float* PI   = (const float*)d_in[4];
  const float* MUs  = (const float*)d_in[5];
  const float* PREs = (const float*)d_in[6];
  const int*   rowv = (const int*)d_in[7];
  const int*   colv = (const int*)d_in[8];
  const int N = in_sizes[0] / 512;   // 100000
  const int E = in_sizes[3];         // 3200000
  float* out = (float*)d_out;

  // workspace layout
  char* ws = (char*)d_ws;
  float* pacc = (float*)ws;                                   // 1 float
  int*   rp   = (int*)(ws + 256);                             // N+1 ints
  size_t rpBytes = (((size_t)(N + 1) * 4) + 255) & ~(size_t)255;
  ushort* s1 = (ushort*)(ws + 256 + rpBytes);                 // N*16 bf16
  float*  s2 = (float*)(ws + 256 + rpBytes + (((size_t)N * 16 * 2 + 255) & ~(size_t)255));

  // dk1/dk2: fold-like split of key(42) = (0, 42)
  uint32_t d10, d11, d20, d21;
  threefry2x32(0u, 42u, 0u, 0u, &d10, &d11);  // dk1
  threefry2x32(0u, 42u, 0u, 1u, &d20, &d21);  // dk2

  int nb0 = (N + 1 + 255) / 256;
  k_init<<<nb0, 256, 0, stream>>>(rowv, rp, pacc, N, E);
  int ntiles = N / 16;                         // N = 100000, divisible by 16
  int nb1 = (ntiles + 3) / 4;
  k_gemm1<<<nb1, 256, 0, stream>>>(x, W1, s1, d10, d11, ntiles);
  int nb2 = (N + 15) / 16;
  k_spmm1<<<nb2, 256, 0, stream>>>(adj, colv, rp, s1, PI, MUs, PREs, W2,
                                   s2, pacc, d20, d21, N);
  k_spmm2<<<nb2, 256, 0, stream>>>(adj, colv, rp, s2, out, N);
  k_fin<<<1, 64, 0, stream>>>(pacc, out, N);
}